// Round 2
// baseline (1436.265 us; speedup 1.0000x reference)
//
#include <hip/hip_runtime.h>
#include <hip/hip_bf16.h>

#define DIM 128
#define ROWS 128
#define APAD 130   // bf16 elements per LDS row (128 + 2 pad) -> <=2-way bank alias (free)
#define TPAD 17    // f32 tile row stride

// ---------------------------------------------------------------------------
// Detect whether edge_index is int64 or int32.
// int64: values < 2^17 => every high u32 word of the first 128 entries is 0.
// int32: those words are random indices in [0,100000) -> ~never all zero.
// ---------------------------------------------------------------------------
__global__ void detect_kernel(const unsigned int* __restrict__ e, int* __restrict__ flags) {
    if (blockIdx.x == 0 && threadIdx.x == 0) {
        int ok64 = 1;
        for (int t = 0; t < 128; ++t) {
            if (e[2 * t + 1] != 0u) { ok64 = 0; break; }
        }
        flags[0] = ok64;
    }
}

__global__ void zero_kernel(float4* __restrict__ agg4, int nagg4,
                            float* __restrict__ deg, int ndeg) {
    int stride = gridDim.x * blockDim.x;
    for (int t = blockIdx.x * blockDim.x + threadIdx.x; t < nagg4; t += stride)
        agg4[t] = make_float4(0.f, 0.f, 0.f, 0.f);
    for (int t = blockIdx.x * blockDim.x + threadIdx.x; t < ndeg; t += stride)
        deg[t] = 0.f;
}

// ---------------------------------------------------------------------------
// Edge scatter: thread t handles edge e = t/32, dims d4 = (t%32)*4.
// Gather x[src] (float4, coalesced; x is L3-resident), weight, atomicAdd into agg.
// Lane group per edge is wave-uniform for src/dst/w -> broadcast loads.
// ---------------------------------------------------------------------------
__global__ __launch_bounds__(256) void scatter_kernel(
        const float* __restrict__ x, const void* __restrict__ eidx,
        const float* __restrict__ ew, float* __restrict__ agg,
        float* __restrict__ deg, const int* __restrict__ flags, int E) {
    int t = blockIdx.x * blockDim.x + threadIdx.x;
    int total = E * 32;
    if (t >= total) return;
    int e = t >> 5;
    int d4 = (t & 31) << 2;
    int src, dst;
    if (flags[0]) {
        const long long* p = (const long long*)eidx;
        src = (int)p[e];
        dst = (int)p[E + e];
    } else {
        const int* p = (const int*)eidx;
        src = p[e];
        dst = p[E + e];
    }
    float w = ew[e];
    float4 v = *(const float4*)(x + (size_t)src * DIM + d4);
    float* a = agg + (size_t)dst * DIM + d4;
    atomicAdd(a + 0, v.x * w);
    atomicAdd(a + 1, v.y * w);
    atomicAdd(a + 2, v.z * w);
    atomicAdd(a + 3, v.w * w);
    if ((t & 31) == 0) atomicAdd(deg + dst, 1.0f);
}

// ---------------------------------------------------------------------------
// Finish: per block of 128 nodes:
//   1) stage agg/max(deg,1) rows into LDS as bf16 (padded, conflict-free)
//   2) thread = node; for each 16-wide output-dim chunk: 128-long dot with W.
//      W addresses are wave-uniform -> compiler emits scalar loads (SGPR file),
//      16 independent FMA chains per thread -> FMA-throughput bound.
//   3) transpose chunk through small LDS tile -> coalesced f32 stores of
//      x + alpha*(dot + b).
// ---------------------------------------------------------------------------
__global__ __launch_bounds__(128) void finish_kernel(
        const float* __restrict__ agg, const float* __restrict__ deg,
        const float* __restrict__ x, const float* __restrict__ W,
        const float* __restrict__ bias, const float* __restrict__ alphaP,
        float* __restrict__ out, int nn) {
    __shared__ __hip_bfloat16 arow[ROWS * APAD];   // 33.3 KB
    __shared__ float tile[ROWS * TPAD];            //  8.7 KB
    const int tid = threadIdx.x;
    const int b0 = blockIdx.x * ROWS;
    const float alpha = alphaP[0];

    // stage rows (one row per iteration, lanes coalesced over k)
    for (int r = 0; r < ROWS; ++r) {
        int node = b0 + r;
        if (node >= nn) break;   // uniform across block (r doesn't depend on tid)
        float dg = deg[node];
        float inv = 1.0f / fmaxf(dg, 1.0f);
        float v = agg[(size_t)node * DIM + tid] * inv;
        arow[r * APAD + tid] = __float2bfloat16(v);
    }
    __syncthreads();

    const int i = tid;  // node owned by this thread (row within block)
    for (int jc = 0; jc < 8; ++jc) {
        const int jb = jc * 16;
        float acc[16];
        #pragma unroll
        for (int u = 0; u < 16; ++u) acc[u] = 0.f;

        for (int k = 0; k < DIM; ++k) {
            float a = __bfloat162float(arow[i * APAD + k]);  // lanes: distinct banks
            #pragma unroll
            for (int u = 0; u < 16; ++u)
                acc[u] = fmaf(a, W[(jb + u) * DIM + k], acc[u]);  // uniform -> s_load
        }

        __syncthreads();   // previous iteration's tile reads complete
        #pragma unroll
        for (int u = 0; u < 16; ++u) tile[i * TPAD + u] = acc[u];
        __syncthreads();

        // cooperative transpose-write: 128 rows x 16 cols, f32 out
        for (int t2 = tid; t2 < ROWS * 16; t2 += 128) {
            int r = t2 >> 4, c = t2 & 15;
            int node = b0 + r;
            if (node < nn) {
                int j = jb + c;
                float val = x[(size_t)node * DIM + j] + alpha * (tile[r * TPAD + c] + bias[j]);
                out[(size_t)node * DIM + j] = val;
            }
        }
    }
}

extern "C" void kernel_launch(void* const* d_in, const int* in_sizes, int n_in,
                              void* d_out, int out_size, void* d_ws, size_t ws_size,
                              hipStream_t stream) {
    // setup_inputs order: x(0), edge_index(1), num_nodes(2), edge_weight(3), W(4), b(5), alpha(6)
    const float* x      = (const float*)d_in[0];
    const void*  eidx   = d_in[1];
    const float* ew     = (const float*)d_in[3];
    const float* W      = (const float*)d_in[4];
    const float* bias   = (const float*)d_in[5];
    const float* alphaP = (const float*)d_in[6];

    const int NN = in_sizes[0] / DIM;   // robust num_nodes (avoid reading device scalar)
    const int E  = in_sizes[3];

    // ws layout: agg f32 [NN*DIM] | deg f32 [NN] | flags int[2]
    float* agg  = (float*)d_ws;
    float* deg  = (float*)((char*)d_ws + (size_t)NN * DIM * sizeof(float));
    int*  flags = (int*)((char*)d_ws + (size_t)NN * DIM * sizeof(float) + (size_t)NN * sizeof(float));

    float* out = (float*)d_out;

    detect_kernel<<<1, 64, 0, stream>>>((const unsigned int*)eidx, flags);

    int nagg4 = NN * (DIM / 4);
    zero_kernel<<<2048, 256, 0, stream>>>((float4*)agg, nagg4, deg, NN);

    int total  = E * 32;
    int blocks = (total + 255) / 256;
    scatter_kernel<<<blocks, 256, 0, stream>>>(x, eidx, ew, agg, deg, flags, E);

    int fblocks = (NN + ROWS - 1) / ROWS;
    finish_kernel<<<fblocks, 128, 0, stream>>>(agg, deg, x, W, bias, alphaP, out, NN);
}

// Round 3
// 462.583 us; speedup vs baseline: 3.1049x; 3.1049x over previous
//
#include <hip/hip_runtime.h>
#include <hip/hip_bf16.h>

#define DIM 128
#define ROWS 128
#define APAD 130   // bf16 elements per LDS row (128 + 2 pad) -> 2-way bank alias (free)
#define TPAD 17    // f32 tile row stride

#define SCAN_TPB 256
#define SCAN_EPT 4
#define SCAN_CHUNK (SCAN_TPB * SCAN_EPT)   // 1024 elements per scan block

// ---------------------------------------------------------------------------
// Detect whether edge_index is int64 or int32 (values < 2^17 => int64 high
// words of first 128 entries are all zero; int32 data there is random).
// ---------------------------------------------------------------------------
__global__ void detect_kernel(const unsigned int* __restrict__ e, int* __restrict__ flags) {
    if (blockIdx.x == 0 && threadIdx.x == 0) {
        int ok64 = 1;
        for (int t = 0; t < 128; ++t) {
            if (e[2 * t + 1] != 0u) { ok64 = 0; break; }
        }
        flags[0] = ok64;
    }
}

__global__ void zero_int_kernel(int* __restrict__ p, int n) {
    int stride = gridDim.x * blockDim.x;
    for (int t = blockIdx.x * blockDim.x + threadIdx.x; t < n; t += stride) p[t] = 0;
}

__device__ __forceinline__ int load_dst(const void* eidx, int flag64, int E, int e) {
    return flag64 ? (int)((const long long*)eidx)[E + e] : ((const int*)eidx)[E + e];
}
__device__ __forceinline__ int load_src(const void* eidx, int flag64, int E, int e) {
    return flag64 ? (int)((const long long*)eidx)[e] : ((const int*)eidx)[e];
}

// ---------------------------------------------------------------------------
// CSR build: histogram -> 3-kernel exclusive scan -> slot fill
// ---------------------------------------------------------------------------
__global__ void hist_kernel(const void* __restrict__ eidx, int* __restrict__ cnt,
                            const int* __restrict__ flags, int E) {
    int e = blockIdx.x * blockDim.x + threadIdx.x;
    if (e >= E) return;
    atomicAdd(&cnt[load_dst(eidx, flags[0], E, e)], 1);
}

__global__ __launch_bounds__(SCAN_TPB) void scan1_kernel(
        const int* __restrict__ cnt, int* __restrict__ rowstart,
        int* __restrict__ blockSums, int nn) {
    __shared__ int s[SCAN_TPB];
    const int base = blockIdx.x * SCAN_CHUNK;
    const int tid = threadIdx.x;
    int v[SCAN_EPT];
    int tsum = 0;
    #pragma unroll
    for (int u = 0; u < SCAN_EPT; ++u) {
        int i = base + tid * SCAN_EPT + u;
        int c = (i < nn) ? cnt[i] : 0;
        v[u] = tsum;             // exclusive prefix within thread
        tsum += c;
    }
    s[tid] = tsum;
    __syncthreads();
    for (int off = 1; off < SCAN_TPB; off <<= 1) {
        int t = (tid >= off) ? s[tid - off] : 0;
        __syncthreads();
        s[tid] += t;
        __syncthreads();
    }
    int ex = s[tid] - tsum;      // exclusive prefix of this thread's chunk
    #pragma unroll
    for (int u = 0; u < SCAN_EPT; ++u) {
        int i = base + tid * SCAN_EPT + u;
        if (i < nn) rowstart[i] = ex + v[u];
    }
    if (tid == SCAN_TPB - 1) blockSums[blockIdx.x] = s[tid];
}

__global__ __launch_bounds__(1024) void scan2_kernel(
        const int* __restrict__ blockSums, int* __restrict__ blockOff, int nb) {
    __shared__ int s[1024];
    int tid = threadIdx.x;
    int val = (tid < nb) ? blockSums[tid] : 0;
    s[tid] = val;
    __syncthreads();
    for (int off = 1; off < 1024; off <<= 1) {
        int t = (tid >= off) ? s[tid - off] : 0;
        __syncthreads();
        s[tid] += t;
        __syncthreads();
    }
    if (tid < nb) blockOff[tid] = s[tid] - val;   // exclusive
}

__global__ __launch_bounds__(SCAN_TPB) void scan3_kernel(
        int* __restrict__ rowstart, const int* __restrict__ blockOff, int nn, int E) {
    const int base = blockIdx.x * SCAN_CHUNK;
    const int off = blockOff[blockIdx.x];
    #pragma unroll
    for (int u = 0; u < SCAN_EPT; ++u) {
        int i = base + threadIdx.x + u * SCAN_TPB;
        if (i < nn) rowstart[i] += off;
    }
    if (blockIdx.x == 0 && threadIdx.x == 0) rowstart[nn] = E;
}

__global__ void fill_kernel(const void* __restrict__ eidx, const float* __restrict__ ew,
                            const int* __restrict__ rowstart, int* __restrict__ cursor,
                            uint2* __restrict__ srcw, const int* __restrict__ flags, int E) {
    int e = blockIdx.x * blockDim.x + threadIdx.x;
    if (e >= E) return;
    int f = flags[0];
    int src = load_src(eidx, f, E, e);
    int dst = load_dst(eidx, f, E, e);
    int pos = rowstart[dst] + atomicAdd(&cursor[dst], 1);
    uint2 p;
    p.x = (unsigned)src;
    p.y = __float_as_uint(ew[e]);
    srcw[pos] = p;
}

// ---------------------------------------------------------------------------
// Gather: one wave per node. Lane owns dims [2*lane, 2*lane+1].
// Per edge: wave-uniform (src,w) broadcast load, coalesced 512B x-row gather,
// register FMA. Normalize by 1/max(deg,1), single coalesced row write. No atomics.
// ---------------------------------------------------------------------------
__global__ __launch_bounds__(256) void gather_kernel(
        const float* __restrict__ x, const uint2* __restrict__ srcw,
        const int* __restrict__ rowstart, float* __restrict__ agg, int nn) {
    int gw = (blockIdx.x * blockDim.x + threadIdx.x) >> 6;
    int lane = threadIdx.x & 63;
    if (gw >= nn) return;
    int n0 = rowstart[gw], n1 = rowstart[gw + 1];
    float ax = 0.f, ay = 0.f;
    for (int e = n0; e < n1; ++e) {
        uint2 sw = srcw[e];
        float w = __uint_as_float(sw.y);
        const float2 xr = *(const float2*)(x + (size_t)sw.x * DIM + lane * 2);
        ax = fmaf(xr.x, w, ax);
        ay = fmaf(xr.y, w, ay);
    }
    float inv = 1.0f / fmaxf((float)(n1 - n0), 1.0f);
    float2 o;
    o.x = ax * inv;
    o.y = ay * inv;
    *(float2*)(agg + (size_t)gw * DIM + lane * 2) = o;
}

// ---------------------------------------------------------------------------
// Finish: agg (pre-normalized, lives in d_out) -> out = x + alpha*(agg@W^T + b),
// in place. Per 128-node block: stage rows to bf16 LDS (all reads of ag_out
// complete before any writes), then 16-wide FMA chains with wave-uniform
// scalar W loads, transpose tile, coalesced f32 stores.
// ---------------------------------------------------------------------------
__global__ __launch_bounds__(128) void finish_kernel(
        float* ag_out,                      // agg in, out written in place
        const float* __restrict__ x, const float* __restrict__ W,
        const float* __restrict__ bias, const float* __restrict__ alphaP, int nn) {
    __shared__ __hip_bfloat16 arow[ROWS * APAD];   // 33.3 KB
    __shared__ float tile[ROWS * TPAD];            //  8.7 KB
    const int tid = threadIdx.x;
    const int b0 = blockIdx.x * ROWS;
    const float alpha = alphaP[0];

    for (int r = 0; r < ROWS; ++r) {
        int node = b0 + r;
        if (node >= nn) break;   // uniform across block
        arow[r * APAD + tid] = __float2bfloat16(ag_out[(size_t)node * DIM + tid]);
    }
    __syncthreads();

    const int i = tid;
    for (int jc = 0; jc < 8; ++jc) {
        const int jb = jc * 16;
        float acc[16];
        #pragma unroll
        for (int u = 0; u < 16; ++u) acc[u] = 0.f;

        for (int k = 0; k < DIM; ++k) {
            float a = __bfloat162float(arow[i * APAD + k]);
            #pragma unroll
            for (int u = 0; u < 16; ++u)
                acc[u] = fmaf(a, W[(jb + u) * DIM + k], acc[u]);   // uniform -> s_load
        }

        __syncthreads();
        #pragma unroll
        for (int u = 0; u < 16; ++u) tile[i * TPAD + u] = acc[u];
        __syncthreads();

        for (int t2 = tid; t2 < ROWS * 16; t2 += 128) {
            int r = t2 >> 4, c = t2 & 15;
            int node = b0 + r;
            if (node < nn) {
                int j = jb + c;
                float val = x[(size_t)node * DIM + j] + alpha * (tile[r * TPAD + c] + bias[j]);
                ag_out[(size_t)node * DIM + j] = val;
            }
        }
    }
}

extern "C" void kernel_launch(void* const* d_in, const int* in_sizes, int n_in,
                              void* d_out, int out_size, void* d_ws, size_t ws_size,
                              hipStream_t stream) {
    // inputs: x(0), edge_index(1), num_nodes(2), edge_weight(3), W(4), b(5), alpha(6)
    const float* x      = (const float*)d_in[0];
    const void*  eidx   = d_in[1];
    const float* ew     = (const float*)d_in[3];
    const float* W      = (const float*)d_in[4];
    const float* bias   = (const float*)d_in[5];
    const float* alphaP = (const float*)d_in[6];

    const int NN = in_sizes[0] / DIM;
    const int E  = in_sizes[3];

    // ws layout: srcw uint2[E] | cnt int[NN] | cursor int[NN] | rowstart int[NN+1]
    //            | blockSums int[1024] | blockOff int[1024] | flags int[2]   (~6.4 MB)
    uint2* srcw     = (uint2*)d_ws;
    int*   cnt      = (int*)(srcw + E);
    int*   cursor   = cnt + NN;
    int*   rowstart = cursor + NN;
    int*   blockSums= rowstart + NN + 1;
    int*   blockOff = blockSums + 1024;
    int*   flags    = blockOff + 1024;

    float* agg = (float*)d_out;   // agg lives in d_out; finish rewrites in place

    detect_kernel<<<1, 64, 0, stream>>>((const unsigned int*)eidx, flags);

    zero_int_kernel<<<256, 256, 0, stream>>>(cnt, 2 * NN);   // cnt + cursor contiguous

    int eblocks = (E + 255) / 256;
    hist_kernel<<<eblocks, 256, 0, stream>>>(eidx, cnt, flags, E);

    int nscan = (NN + SCAN_CHUNK - 1) / SCAN_CHUNK;          // 98 for NN=100K (<=1024)
    scan1_kernel<<<nscan, SCAN_TPB, 0, stream>>>(cnt, rowstart, blockSums, NN);
    scan2_kernel<<<1, 1024, 0, stream>>>(blockSums, blockOff, nscan);
    scan3_kernel<<<nscan, SCAN_TPB, 0, stream>>>(rowstart, blockOff, NN, E);

    fill_kernel<<<eblocks, 256, 0, stream>>>(eidx, ew, rowstart, cursor, srcw, flags, E);

    int gblocks = (NN + 3) / 4;                               // 4 waves/block, 1 node/wave
    gather_kernel<<<gblocks, 256, 0, stream>>>(x, srcw, rowstart, agg, NN);

    int fblocks = (NN + ROWS - 1) / ROWS;
    finish_kernel<<<fblocks, 128, 0, stream>>>(agg, x, W, bias, alphaP, NN);
}

// Round 4
// 192.333 us; speedup vs baseline: 7.4676x; 2.4051x over previous
//
#include <hip/hip_runtime.h>
#include <hip/hip_bf16.h>

#define DIM 128

#define SCAN_TPB 256
#define SCAN_EPT 4
#define SCAN_CHUNK (SCAN_TPB * SCAN_EPT)   // 1024 elements per scan block

// finish kernel geometry
#define FROWS 64      // M-tile rows per block
#define FPAD 136      // bf16 row stride in LDS (64B-aligned-ish, 16B aligned, 2-way bank alias only)

typedef __attribute__((ext_vector_type(8))) short bf16x8;
typedef __attribute__((ext_vector_type(4))) float f32x4;

__device__ __forceinline__ short f2bf(float f) {
    union { __hip_bfloat16 h; short s; } u;
    u.h = __float2bfloat16(f);
    return u.s;
}

// ---------------------------------------------------------------------------
// Detect whether edge_index is int64 or int32 (values < 2^17 => int64 high
// words of first 128 entries are all zero; int32 data there is random).
// ---------------------------------------------------------------------------
__global__ void detect_kernel(const unsigned int* __restrict__ e, int* __restrict__ flags) {
    if (blockIdx.x == 0 && threadIdx.x == 0) {
        int ok64 = 1;
        for (int t = 0; t < 128; ++t) {
            if (e[2 * t + 1] != 0u) { ok64 = 0; break; }
        }
        flags[0] = ok64;
    }
}

__global__ void zero_int_kernel(int* __restrict__ p, int n) {
    int stride = gridDim.x * blockDim.x;
    for (int t = blockIdx.x * blockDim.x + threadIdx.x; t < n; t += stride) p[t] = 0;
}

__device__ __forceinline__ int load_dst(const void* eidx, int flag64, int E, int e) {
    return flag64 ? (int)((const long long*)eidx)[E + e] : ((const int*)eidx)[E + e];
}
__device__ __forceinline__ int load_src(const void* eidx, int flag64, int E, int e) {
    return flag64 ? (int)((const long long*)eidx)[e] : ((const int*)eidx)[e];
}

// ---------------------------------------------------------------------------
// CSR build: histogram -> 3-kernel exclusive scan -> slot fill
// ---------------------------------------------------------------------------
__global__ void hist_kernel(const void* __restrict__ eidx, int* __restrict__ cnt,
                            const int* __restrict__ flags, int E) {
    int e = blockIdx.x * blockDim.x + threadIdx.x;
    if (e >= E) return;
    atomicAdd(&cnt[load_dst(eidx, flags[0], E, e)], 1);
}

__global__ __launch_bounds__(SCAN_TPB) void scan1_kernel(
        const int* __restrict__ cnt, int* __restrict__ rowstart,
        int* __restrict__ blockSums, int nn) {
    __shared__ int s[SCAN_TPB];
    const int base = blockIdx.x * SCAN_CHUNK;
    const int tid = threadIdx.x;
    int v[SCAN_EPT];
    int tsum = 0;
    #pragma unroll
    for (int u = 0; u < SCAN_EPT; ++u) {
        int i = base + tid * SCAN_EPT + u;
        int c = (i < nn) ? cnt[i] : 0;
        v[u] = tsum;
        tsum += c;
    }
    s[tid] = tsum;
    __syncthreads();
    for (int off = 1; off < SCAN_TPB; off <<= 1) {
        int t = (tid >= off) ? s[tid - off] : 0;
        __syncthreads();
        s[tid] += t;
        __syncthreads();
    }
    int ex = s[tid] - tsum;
    #pragma unroll
    for (int u = 0; u < SCAN_EPT; ++u) {
        int i = base + tid * SCAN_EPT + u;
        if (i < nn) rowstart[i] = ex + v[u];
    }
    if (tid == SCAN_TPB - 1) blockSums[blockIdx.x] = s[tid];
}

__global__ __launch_bounds__(1024) void scan2_kernel(
        const int* __restrict__ blockSums, int* __restrict__ blockOff, int nb) {
    __shared__ int s[1024];
    int tid = threadIdx.x;
    int val = (tid < nb) ? blockSums[tid] : 0;
    s[tid] = val;
    __syncthreads();
    for (int off = 1; off < 1024; off <<= 1) {
        int t = (tid >= off) ? s[tid - off] : 0;
        __syncthreads();
        s[tid] += t;
        __syncthreads();
    }
    if (tid < nb) blockOff[tid] = s[tid] - val;
}

__global__ __launch_bounds__(SCAN_TPB) void scan3_kernel(
        int* __restrict__ rowstart, const int* __restrict__ blockOff, int nn, int E) {
    const int base = blockIdx.x * SCAN_CHUNK;
    const int off = blockOff[blockIdx.x];
    #pragma unroll
    for (int u = 0; u < SCAN_EPT; ++u) {
        int i = base + threadIdx.x + u * SCAN_TPB;
        if (i < nn) rowstart[i] += off;
    }
    if (blockIdx.x == 0 && threadIdx.x == 0) rowstart[nn] = E;
}

__global__ void fill_kernel(const void* __restrict__ eidx, const float* __restrict__ ew,
                            const int* __restrict__ rowstart, int* __restrict__ cursor,
                            uint2* __restrict__ srcw, const int* __restrict__ flags, int E) {
    int e = blockIdx.x * blockDim.x + threadIdx.x;
    if (e >= E) return;
    int f = flags[0];
    int src = load_src(eidx, f, E, e);
    int dst = load_dst(eidx, f, E, e);
    int pos = rowstart[dst] + atomicAdd(&cursor[dst], 1);
    uint2 p;
    p.x = (unsigned)src;
    p.y = __float_as_uint(ew[e]);
    srcw[pos] = p;
}

// ---------------------------------------------------------------------------
// Gather: one wave per node. Lane owns dims [2*lane, 2*lane+1].
// Per edge: wave-uniform (src,w) broadcast load, coalesced 512B x-row gather,
// register FMA. Normalize by 1/max(deg,1), single coalesced row write. No atomics.
// ---------------------------------------------------------------------------
__global__ __launch_bounds__(256) void gather_kernel(
        const float* __restrict__ x, const uint2* __restrict__ srcw,
        const int* __restrict__ rowstart, float* __restrict__ agg, int nn) {
    int gw = (blockIdx.x * blockDim.x + threadIdx.x) >> 6;
    int lane = threadIdx.x & 63;
    if (gw >= nn) return;
    int n0 = rowstart[gw], n1 = rowstart[gw + 1];
    float ax = 0.f, ay = 0.f;
    for (int e = n0; e < n1; ++e) {
        uint2 sw = srcw[e];
        float w = __uint_as_float(sw.y);
        const float2 xr = *(const float2*)(x + (size_t)sw.x * DIM + lane * 2);
        ax = fmaf(xr.x, w, ax);
        ay = fmaf(xr.y, w, ay);
    }
    float inv = 1.0f / fmaxf((float)(n1 - n0), 1.0f);
    float2 o;
    o.x = ax * inv;
    o.y = ay * inv;
    *(float2*)(agg + (size_t)gw * DIM + lane * 2) = o;
}

// ---------------------------------------------------------------------------
// MFMA finish: out = x + alpha*(agg @ W^T + b), agg pre-normalized in d_out,
// rewritten in place. 512 threads = 8 waves; 64-row M-tile per block.
//  - stage 64 agg rows to LDS as bf16 [64][FPAD] (2-way bank alias only)
//  - wave w owns output cols [16w,16w+16): 4 K-tile B-frags of W held in
//    registers (loaded once from L2-resident W, K-contiguous per lane)
//  - per 16-row sub-tile: 4 ds_read_b128 A-frags + 4 mfma_f32_16x16x32_bf16
//  - epilogue fuses x + alpha*(acc + bias); C/D map: col=lane&15,
//    row=(lane>>4)*4+reg  [verified layout, learn_hip m89/m91]
// ---------------------------------------------------------------------------
__global__ __launch_bounds__(512) void finish_kernel(
        float* ag_out,                      // agg in, out written in place (d_out)
        const float* __restrict__ x, const float* __restrict__ W,
        const float* __restrict__ bias, const float* __restrict__ alphaP, int nn) {
    __shared__ unsigned short A_lds[FROWS * FPAD];   // 17408 B
    const int tid  = threadIdx.x;
    const int wv   = tid >> 6;          // wave 0..7
    const int lane = tid & 63;
    const int half = lane >> 4;         // 0..3 (K-group / row-group)
    const int l16  = lane & 15;         // M-row for A, N-col for B and C/D
    const int b0   = blockIdx.x * FROWS;
    const float alpha = alphaP[0];

    // ---- B-frags: W[jb+l16][kt*32 + half*8 .. +8] as bf16, once per wave ----
    const int jcol = wv * 16 + l16;
    bf16x8 bfrag[4];
    #pragma unroll
    for (int kt = 0; kt < 4; ++kt) {
        const float4* w4 = (const float4*)(W + (size_t)jcol * DIM + kt * 32 + half * 8);
        float4 lo = w4[0], hi = w4[1];
        bf16x8 b;
        b[0] = f2bf(lo.x); b[1] = f2bf(lo.y); b[2] = f2bf(lo.z); b[3] = f2bf(lo.w);
        b[4] = f2bf(hi.x); b[5] = f2bf(hi.y); b[6] = f2bf(hi.z); b[7] = f2bf(hi.w);
        bfrag[kt] = b;
    }
    const float bias_j = bias[jcol];

    // ---- stage 64 agg rows -> bf16 LDS (packed u32 writes, coalesced reads) --
    #pragma unroll
    for (int it = 0; it < 8; ++it) {
        int p = it * 512 + tid;          // 4096 float2-pairs total
        int row = p >> 6;                // 0..63
        int col2 = p & 63;               // pair index 0..63
        int node = b0 + row;
        unsigned int val = 0;
        if (node < nn) {
            float2 v = *(const float2*)(ag_out + (size_t)node * DIM + col2 * 2);
            val = (unsigned int)(unsigned short)f2bf(v.x)
                | ((unsigned int)(unsigned short)f2bf(v.y) << 16);
        }
        ((unsigned int*)A_lds)[row * (FPAD / 2) + col2] = val;
    }
    __syncthreads();

    // ---- 4 sub-tiles of 16 rows: MFMA + fused epilogue ----
    #pragma unroll
    for (int mt = 0; mt < 4; ++mt) {
        f32x4 acc = {0.f, 0.f, 0.f, 0.f};
        #pragma unroll
        for (int kt = 0; kt < 4; ++kt) {
            const bf16x8 a = *(const bf16x8*)&A_lds[(mt * 16 + l16) * FPAD + kt * 32 + half * 8];
            acc = __builtin_amdgcn_mfma_f32_16x16x32_bf16(a, bfrag[kt], acc, 0, 0, 0);
        }
        #pragma unroll
        for (int r = 0; r < 4; ++r) {
            int grow = b0 + mt * 16 + half * 4 + r;
            if (grow < nn) {
                size_t idx = (size_t)grow * DIM + jcol;
                ag_out[idx] = x[idx] + alpha * (acc[r] + bias_j);
            }
        }
    }
}

extern "C" void kernel_launch(void* const* d_in, const int* in_sizes, int n_in,
                              void* d_out, int out_size, void* d_ws, size_t ws_size,
                              hipStream_t stream) {
    // inputs: x(0), edge_index(1), num_nodes(2), edge_weight(3), W(4), b(5), alpha(6)
    const float* x      = (const float*)d_in[0];
    const void*  eidx   = d_in[1];
    const float* ew     = (const float*)d_in[3];
    const float* W      = (const float*)d_in[4];
    const float* bias   = (const float*)d_in[5];
    const float* alphaP = (const float*)d_in[6];

    const int NN = in_sizes[0] / DIM;
    const int E  = in_sizes[3];

    // ws layout: srcw uint2[E] | cnt int[NN] | cursor int[NN] | rowstart int[NN+1]
    //            | blockSums int[1024] | blockOff int[1024] | flags int[2]   (~6.4 MB)
    uint2* srcw     = (uint2*)d_ws;
    int*   cnt      = (int*)(srcw + E);
    int*   cursor   = cnt + NN;
    int*   rowstart = cursor + NN;
    int*   blockSums= rowstart + NN + 1;
    int*   blockOff = blockSums + 1024;
    int*   flags    = blockOff + 1024;

    float* agg = (float*)d_out;   // agg lives in d_out; finish rewrites in place

    detect_kernel<<<1, 64, 0, stream>>>((const unsigned int*)eidx, flags);

    zero_int_kernel<<<256, 256, 0, stream>>>(cnt, 2 * NN);   // cnt + cursor contiguous

    int eblocks = (E + 255) / 256;
    hist_kernel<<<eblocks, 256, 0, stream>>>(eidx, cnt, flags, E);

    int nscan = (NN + SCAN_CHUNK - 1) / SCAN_CHUNK;          // 98 for NN=100K (<=1024)
    scan1_kernel<<<nscan, SCAN_TPB, 0, stream>>>(cnt, rowstart, blockSums, NN);
    scan2_kernel<<<1, 1024, 0, stream>>>(blockSums, blockOff, nscan);
    scan3_kernel<<<nscan, SCAN_TPB, 0, stream>>>(rowstart, blockOff, NN, E);

    fill_kernel<<<eblocks, 256, 0, stream>>>(eidx, ew, rowstart, cursor, srcw, flags, E);

    int gblocks = (NN + 3) / 4;                               // 4 waves/block, 1 node/wave
    gather_kernel<<<gblocks, 256, 0, stream>>>(x, srcw, rowstart, agg, NN);

    int fblocks = (NN + FROWS - 1) / FROWS;
    finish_kernel<<<fblocks, 512, 0, stream>>>(agg, x, W, bias, alphaP, NN);
}

// Round 5
// 160.330 us; speedup vs baseline: 8.9582x; 1.1996x over previous
//
#include <hip/hip_runtime.h>
#include <hip/hip_bf16.h>

#define DIM 128

#define SCAN_TPB 256
#define SCAN_EPT 4
#define SCAN_CHUNK (SCAN_TPB * SCAN_EPT)   // 1024 elements per scan block

// finish kernel geometry
#define FROWS 64      // M-tile rows per block
#define FPAD 136      // bf16 row stride in LDS: 272B -> 2-way bank alias on b128 (free)

typedef __attribute__((ext_vector_type(8))) short bf16x8;
typedef __attribute__((ext_vector_type(8))) unsigned short u16x8;
typedef __attribute__((ext_vector_type(4))) float f32x4;

__device__ __forceinline__ short f2bf(float f) {
    union { __hip_bfloat16 h; short s; } u;
    u.h = __float2bfloat16(f);   // round-to-nearest-even
    return u.s;
}
__device__ __forceinline__ float bf2f(unsigned short s) {
    union { unsigned int u; float f; } c;
    c.u = ((unsigned int)s) << 16;
    return c.f;
}

// ---------------------------------------------------------------------------
// Detect whether edge_index is int64 or int32 (values < 2^17 => int64 high
// words of first 128 entries are all zero; int32 data there is random).
// ---------------------------------------------------------------------------
__global__ void detect_kernel(const unsigned int* __restrict__ e, int* __restrict__ flags) {
    if (blockIdx.x == 0 && threadIdx.x == 0) {
        int ok64 = 1;
        for (int t = 0; t < 128; ++t) {
            if (e[2 * t + 1] != 0u) { ok64 = 0; break; }
        }
        flags[0] = ok64;
    }
}

__global__ void zero_int_kernel(int* __restrict__ p, int n) {
    int stride = gridDim.x * blockDim.x;
    for (int t = blockIdx.x * blockDim.x + threadIdx.x; t < n; t += stride) p[t] = 0;
}

// x (f32) -> xb (bf16), 8 elems/thread/iter
__global__ __launch_bounds__(256) void cvt_kernel(const float* __restrict__ x,
        unsigned short* __restrict__ xb, int n8) {
    int stride = gridDim.x * blockDim.x;
    for (int t = blockIdx.x * blockDim.x + threadIdx.x; t < n8; t += stride) {
        const float4* p = (const float4*)(x + (size_t)t * 8);
        float4 a = p[0], b = p[1];
        u16x8 o;
        o[0] = (unsigned short)f2bf(a.x); o[1] = (unsigned short)f2bf(a.y);
        o[2] = (unsigned short)f2bf(a.z); o[3] = (unsigned short)f2bf(a.w);
        o[4] = (unsigned short)f2bf(b.x); o[5] = (unsigned short)f2bf(b.y);
        o[6] = (unsigned short)f2bf(b.z); o[7] = (unsigned short)f2bf(b.w);
        *(u16x8*)(xb + (size_t)t * 8) = o;
    }
}

__device__ __forceinline__ int load_dst(const void* eidx, int flag64, int E, int e) {
    return flag64 ? (int)((const long long*)eidx)[E + e] : ((const int*)eidx)[E + e];
}
__device__ __forceinline__ int load_src(const void* eidx, int flag64, int E, int e) {
    return flag64 ? (int)((const long long*)eidx)[e] : ((const int*)eidx)[e];
}

// ---------------------------------------------------------------------------
// CSR build: histogram -> 3-kernel exclusive scan -> slot fill
// ---------------------------------------------------------------------------
__global__ void hist_kernel(const void* __restrict__ eidx, int* __restrict__ cnt,
                            const int* __restrict__ flags, int E) {
    int e = blockIdx.x * blockDim.x + threadIdx.x;
    if (e >= E) return;
    atomicAdd(&cnt[load_dst(eidx, flags[0], E, e)], 1);
}

__global__ __launch_bounds__(SCAN_TPB) void scan1_kernel(
        const int* __restrict__ cnt, int* __restrict__ rowstart,
        int* __restrict__ blockSums, int nn) {
    __shared__ int s[SCAN_TPB];
    const int base = blockIdx.x * SCAN_CHUNK;
    const int tid = threadIdx.x;
    int v[SCAN_EPT];
    int tsum = 0;
    #pragma unroll
    for (int u = 0; u < SCAN_EPT; ++u) {
        int i = base + tid * SCAN_EPT + u;
        int c = (i < nn) ? cnt[i] : 0;
        v[u] = tsum;
        tsum += c;
    }
    s[tid] = tsum;
    __syncthreads();
    for (int off = 1; off < SCAN_TPB; off <<= 1) {
        int t = (tid >= off) ? s[tid - off] : 0;
        __syncthreads();
        s[tid] += t;
        __syncthreads();
    }
    int ex = s[tid] - tsum;
    #pragma unroll
    for (int u = 0; u < SCAN_EPT; ++u) {
        int i = base + tid * SCAN_EPT + u;
        if (i < nn) rowstart[i] = ex + v[u];
    }
    if (tid == SCAN_TPB - 1) blockSums[blockIdx.x] = s[tid];
}

__global__ __launch_bounds__(1024) void scan2_kernel(
        const int* __restrict__ blockSums, int* __restrict__ blockOff, int nb) {
    __shared__ int s[1024];
    int tid = threadIdx.x;
    int val = (tid < nb) ? blockSums[tid] : 0;
    s[tid] = val;
    __syncthreads();
    for (int off = 1; off < 1024; off <<= 1) {
        int t = (tid >= off) ? s[tid - off] : 0;
        __syncthreads();
        s[tid] += t;
        __syncthreads();
    }
    if (tid < nb) blockOff[tid] = s[tid] - val;
}

__global__ __launch_bounds__(SCAN_TPB) void scan3_kernel(
        int* __restrict__ rowstart, const int* __restrict__ blockOff, int nn, int E) {
    const int base = blockIdx.x * SCAN_CHUNK;
    const int off = blockOff[blockIdx.x];
    #pragma unroll
    for (int u = 0; u < SCAN_EPT; ++u) {
        int i = base + threadIdx.x + u * SCAN_TPB;
        if (i < nn) rowstart[i] += off;
    }
    if (blockIdx.x == 0 && threadIdx.x == 0) rowstart[nn] = E;
}

__global__ void fill_kernel(const void* __restrict__ eidx, const float* __restrict__ ew,
                            const int* __restrict__ rowstart, int* __restrict__ cursor,
                            uint2* __restrict__ srcw, const int* __restrict__ flags, int E) {
    int e = blockIdx.x * blockDim.x + threadIdx.x;
    if (e >= E) return;
    int f = flags[0];
    int src = load_src(eidx, f, E, e);
    int dst = load_dst(eidx, f, E, e);
    int pos = rowstart[dst] + atomicAdd(&cursor[dst], 1);
    uint2 p;
    p.x = (unsigned)src;
    p.y = __float_as_uint(ew[e]);
    srcw[pos] = p;
}

// ---------------------------------------------------------------------------
// Gather: 4 nodes per wave (16 lanes per node, lane owns 8 dims = 16B bf16).
// Per edge: 16-lane-uniform (src,w) broadcast load + 256B coalesced bf16 row
// gather. 2-edge manual unroll -> up to 8 row-fetches in flight per wave.
// Normalize by 1/max(deg,1); write bf16 agg row (256B). No atomics.
// ---------------------------------------------------------------------------
__global__ __launch_bounds__(256) void gather_kernel(
        const unsigned short* __restrict__ xb, const uint2* __restrict__ srcw,
        const int* __restrict__ rowstart, unsigned short* __restrict__ aggb, int nn) {
    int g = (blockIdx.x * blockDim.x + threadIdx.x) >> 4;   // node
    int sub = threadIdx.x & 15;                             // owns dims [8*sub, 8*sub+8)
    if (g >= nn) return;
    int n0 = rowstart[g], n1 = rowstart[g + 1];
    float acc[8] = {0.f, 0.f, 0.f, 0.f, 0.f, 0.f, 0.f, 0.f};
    int e = n0;
    for (; e + 2 <= n1; e += 2) {
        uint2 sw0 = srcw[e];
        uint2 sw1 = srcw[e + 1];
        u16x8 x0 = *(const u16x8*)(xb + (size_t)sw0.x * DIM + sub * 8);
        u16x8 x1 = *(const u16x8*)(xb + (size_t)sw1.x * DIM + sub * 8);
        float w0 = __uint_as_float(sw0.y);
        float w1 = __uint_as_float(sw1.y);
        #pragma unroll
        for (int j = 0; j < 8; ++j) {
            acc[j] = fmaf(bf2f(x0[j]), w0, acc[j]);
            acc[j] = fmaf(bf2f(x1[j]), w1, acc[j]);
        }
    }
    if (e < n1) {
        uint2 sw = srcw[e];
        u16x8 xr = *(const u16x8*)(xb + (size_t)sw.x * DIM + sub * 8);
        float w = __uint_as_float(sw.y);
        #pragma unroll
        for (int j = 0; j < 8; ++j) acc[j] = fmaf(bf2f(xr[j]), w, acc[j]);
    }
    float inv = 1.0f / fmaxf((float)(n1 - n0), 1.0f);
    u16x8 o;
    #pragma unroll
    for (int j = 0; j < 8; ++j) o[j] = (unsigned short)f2bf(acc[j] * inv);
    *(u16x8*)(aggb + (size_t)g * DIM + sub * 8) = o;
}

// ---------------------------------------------------------------------------
// MFMA finish: out = x + alpha*(aggb @ W^T + b). aggb is bf16 in ws; out is
// d_out (overwrites the xb scratch parked there, which is dead by now).
// 512 threads = 8 waves; 64-row M-tile; wave w owns output cols [16w,16w+16).
// C/D map: col=lane&15, row=(lane>>4)*4+reg  [verified, learn_hip m89/m91]
// ---------------------------------------------------------------------------
__global__ __launch_bounds__(512) void finish_kernel(
        const unsigned short* __restrict__ aggb, float* __restrict__ out,
        const float* __restrict__ x, const float* __restrict__ W,
        const float* __restrict__ bias, const float* __restrict__ alphaP, int nn) {
    __shared__ alignas(16) unsigned short A_lds[FROWS * FPAD];   // 17408 B
    const int tid  = threadIdx.x;
    const int wv   = tid >> 6;          // wave 0..7
    const int lane = tid & 63;
    const int half = lane >> 4;         // 0..3 (K-group / row-group)
    const int l16  = lane & 15;         // M-row for A, N-col for B and C/D
    const int b0   = blockIdx.x * FROWS;
    const float alpha = alphaP[0];

    // ---- B-frags: W[jcol][kt*32 + half*8 .. +8] as bf16, loaded once ----
    const int jcol = wv * 16 + l16;
    bf16x8 bfrag[4];
    #pragma unroll
    for (int kt = 0; kt < 4; ++kt) {
        const float4* w4 = (const float4*)(W + (size_t)jcol * DIM + kt * 32 + half * 8);
        float4 lo = w4[0], hi = w4[1];
        bf16x8 b;
        b[0] = f2bf(lo.x); b[1] = f2bf(lo.y); b[2] = f2bf(lo.z); b[3] = f2bf(lo.w);
        b[4] = f2bf(hi.x); b[5] = f2bf(hi.y); b[6] = f2bf(hi.z); b[7] = f2bf(hi.w);
        bfrag[kt] = b;
    }
    const float bias_j = bias[jcol];

    // ---- stage 64 bf16 rows -> LDS: 1024 chunks of 16B, 2 iters ----
    #pragma unroll
    for (int it = 0; it < 2; ++it) {
        int p = it * 512 + tid;          // 0..1023
        int row = p >> 4;                // 0..63
        int c8 = p & 15;                 // 16B chunk within row
        int node = b0 + row;
        u16x8 v = {0, 0, 0, 0, 0, 0, 0, 0};
        if (node < nn) v = *(const u16x8*)(aggb + (size_t)node * DIM + c8 * 8);
        *(u16x8*)&A_lds[row * FPAD + c8 * 8] = v;
    }
    __syncthreads();

    // ---- 4 sub-tiles of 16 rows: MFMA + fused epilogue ----
    #pragma unroll
    for (int mt = 0; mt < 4; ++mt) {
        f32x4 acc = {0.f, 0.f, 0.f, 0.f};
        #pragma unroll
        for (int kt = 0; kt < 4; ++kt) {
            const bf16x8 a = *(const bf16x8*)&A_lds[(mt * 16 + l16) * FPAD + kt * 32 + half * 8];
            acc = __builtin_amdgcn_mfma_f32_16x16x32_bf16(a, bfrag[kt], acc, 0, 0, 0);
        }
        #pragma unroll
        for (int r = 0; r < 4; ++r) {
            int grow = b0 + mt * 16 + half * 4 + r;
            if (grow < nn) {
                size_t idx = (size_t)grow * DIM + jcol;
                out[idx] = x[idx] + alpha * (acc[r] + bias_j);
            }
        }
    }
}

extern "C" void kernel_launch(void* const* d_in, const int* in_sizes, int n_in,
                              void* d_out, int out_size, void* d_ws, size_t ws_size,
                              hipStream_t stream) {
    // inputs: x(0), edge_index(1), num_nodes(2), edge_weight(3), W(4), b(5), alpha(6)
    const float* x      = (const float*)d_in[0];
    const void*  eidx   = d_in[1];
    const float* ew     = (const float*)d_in[3];
    const float* W      = (const float*)d_in[4];
    const float* bias   = (const float*)d_in[5];
    const float* alphaP = (const float*)d_in[6];

    const int NN = in_sizes[0] / DIM;
    const int E  = in_sizes[3];

    // ws layout: aggb u16[NN*DIM] (25.6MB) | srcw uint2[E] (5.1MB) | cnt int[NN]
    //            | cursor int[NN] | rowstart int[NN+1] | blockSums[1024]
    //            | blockOff[1024] | flags[2]   (~32 MB total)
    unsigned short* aggb = (unsigned short*)d_ws;
    uint2* srcw     = (uint2*)(aggb + (size_t)NN * DIM);
    int*   cnt      = (int*)(srcw + E);
    int*   cursor   = cnt + NN;
    int*   rowstart = cursor + NN;
    int*   blockSums= rowstart + NN + 1;
    int*   blockOff = blockSums + 1024;
    int*   flags    = blockOff + 1024;

    // xb (bf16 copy of x) parks in the first half of d_out; dead once finish runs
    unsigned short* xb = (unsigned short*)d_out;
    float* out = (float*)d_out;

    detect_kernel<<<1, 64, 0, stream>>>((const unsigned int*)eidx, flags);

    zero_int_kernel<<<256, 256, 0, stream>>>(cnt, 2 * NN);   // cnt + cursor contiguous

    int n8 = NN * DIM / 8;
    cvt_kernel<<<2048, 256, 0, stream>>>(x, xb, n8);

    int eblocks = (E + 255) / 256;
    hist_kernel<<<eblocks, 256, 0, stream>>>(eidx, cnt, flags, E);

    int nscan = (NN + SCAN_CHUNK - 1) / SCAN_CHUNK;          // 98 for NN=100K
    scan1_kernel<<<nscan, SCAN_TPB, 0, stream>>>(cnt, rowstart, blockSums, NN);
    scan2_kernel<<<1, 1024, 0, stream>>>(blockSums, blockOff, nscan);
    scan3_kernel<<<nscan, SCAN_TPB, 0, stream>>>(rowstart, blockOff, NN, E);

    fill_kernel<<<eblocks, 256, 0, stream>>>(eidx, ew, rowstart, cursor, srcw, flags, E);

    int gblocks = (NN + 15) / 16;                             // 16 nodes per 256-thr block
    gather_kernel<<<gblocks, 256, 0, stream>>>(xb, srcw, rowstart, aggb, NN);

    int fblocks = (NN + FROWS - 1) / FROWS;
    finish_kernel<<<fblocks, 512, 0, stream>>>(aggb, out, x, W, bias, alphaP, NN);
}